// Round 7
// baseline (350.355 us; speedup 1.0000x reference)
//
#include <hip/hip_runtime.h>
#include <hip/hip_fp16.h>

// ---------------------------------------------------------------------------
// VGAE encoder, gather-form, fp16 gather table.
//   a[i] = dis_i*(g[i] + sum_{e:dst=i} g[src_e]),  g = fp16(dis (.) h)
// R12: agg+GEMM fused per 64-node block via LDS epilogue (294 -> 249 us).
// R13 FAILED: coop mega-kernel = 517 us (occupancy halved; latency-bound).
// R14 FAILED: global degree-sort perm = 282 us (scattered locality).
// R15 FAILED: 8x-split finalize = +6.7 us (duplicated histogram work).
// R17: 16 outstanding gathers/wave: only -4.4 us (244.8) -> gather is
//   FILL-RATE-bound (97 MB TCC fetch = 8 XCDs compulsory-missing the 6.4 MB
//   table), not wave-MLP-bound.
// R18: preprocessing rewritten as flat global-atomic primitives (the
//   bucket/ebuf pipeline served only to build es+deg; it cost ~100 us at
//   0.77 blocks/CU with 16.8 MB of intermediates):
//     k_deg:     atomicAdd(&deg[dst],1)                 (391 blocks)
//     k_scan1:   1024-elt block scans + block sums      (98 blocks)
//     k_scanout: starts/cursor/dis/g0 fused elementwise (391 blocks)
//     k_scatter: es[atomicAdd(&cursor[dst],1)] = src    (391 blocks)
//   No ebuf; es (6.4 MB) L2-resident for write combining. Layers = R17.
//   NT loads ONLY on read-once streams (src/dst). NT stores banned (R10).
// ---------------------------------------------------------------------------

#define EPT     16
#define CHUNK   (256 * EPT)        // 4096 edges per block

typedef int   vint4   __attribute__((ext_vector_type(4)));
typedef uint  vuint4  __attribute__((ext_vector_type(4)));
typedef float vfloat4 __attribute__((ext_vector_type(4)));

#define NTL(p) __builtin_nontemporal_load(p)

// ---- P1: degree histogram via global atomics -------------------------------
__global__ __launch_bounds__(256)
void k_deg(const int* __restrict__ dst, int* __restrict__ deg, int E) {
    int e0 = blockIdx.x * CHUNK + threadIdx.x;
#pragma unroll
    for (int i = 0; i < EPT; ++i) {
        int e = e0 + i * 256;
        if (e < E) atomicAdd(&deg[NTL(dst + e)], 1);
    }
}

// ---- P2: block-local scans (1024 ints/block) + block totals ----------------
__global__ __launch_bounds__(256)
void k_scan1(const int* __restrict__ deg, int* __restrict__ tmp,
             int* __restrict__ bsum, int npad) {
    __shared__ int sm[256];
    int t = threadIdx.x;
    int i4 = blockIdx.x * 256 + t;
    int4 v = make_int4(0, 0, 0, 0);
    if (i4 * 4 < npad) v = ((const int4*)deg)[i4];
    int s = v.x + v.y + v.z + v.w;
    sm[t] = s;
    __syncthreads();
    for (int o = 1; o < 256; o <<= 1) {
        int val = (t >= o) ? sm[t - o] : 0;
        __syncthreads();
        sm[t] += val;
        __syncthreads();
    }
    int excl = sm[t] - s;
    if (i4 * 4 < npad) {
        int4 w;
        w.x = excl;
        w.y = excl + v.x;
        w.z = w.y + v.y;
        w.w = w.z + v.z;
        ((int4*)tmp)[i4] = w;
    }
    if (t == 255) bsum[blockIdx.x] = sm[255];
}

// ---- P3: starts/cursor/dis/g0, fused elementwise ---------------------------
// Block covers 256 nodes; chunk = bid>>2 (256-node windows inside 1024-chunks).
__global__ __launch_bounds__(256)
void k_scanout(const int* __restrict__ deg, const int* __restrict__ tmp,
               const int* __restrict__ bsum, int* __restrict__ starts,
               int* __restrict__ cursor, float* __restrict__ dis,
               const float* __restrict__ x, __half* __restrict__ g0,
               int n, int E) {
    __shared__ int   sm[256];
    __shared__ float disL[256];
    int t = threadIdx.x;
    int chunk = blockIdx.x >> 2;          // 1024-chunk index
    int v = (t < chunk) ? bsum[t] : 0;    // chunk <= 97 < 256
    sm[t] = v;
    __syncthreads();
    for (int o = 1; o < 256; o <<= 1) {
        int val = (t >= o) ? sm[t - o] : 0;
        __syncthreads();
        sm[t] += val;
        __syncthreads();
    }
    int pb = sm[255];                     // global prefix of this 1024-chunk
    int node = blockIdx.x * 256 + t;
    float dv = 0.f;
    if (node <= n) {
        int pre = pb + tmp[node];         // prefix at node; at node==n equals E
        starts[node] = pre;
        if (node < n) {
            cursor[node] = pre;
            dv = rsqrtf((float)deg[node] + 1.0f);   // +1 = self loop
            dis[node] = dv;
        }
    }
    disL[t] = dv;
    __syncthreads();
    // g0 = fp16(dis (.) x) for this block's 256 nodes (coalesced 8 B stores)
    int node0 = blockIdx.x * 256;
    const float4* x4 = (const float4*)x;
    uint2* g2 = (uint2*)g0;
    for (int idx = t; idx < 256 * 8; idx += 256) {
        int r = idx >> 3, ln = idx & 7;
        int nd = node0 + r;
        if (nd < n) {
            float d = disL[r];
            float4 vv = x4[(size_t)nd * 8 + ln];
            __half2 lo = __floats2half2_rn(d * vv.x, d * vv.y);
            __half2 hi = __floats2half2_rn(d * vv.z, d * vv.w);
            uint2 u;
            u.x = *(unsigned int*)&lo;
            u.y = *(unsigned int*)&hi;
            g2[(size_t)nd * 8 + ln] = u;
        }
    }
}

// ---- P4: scatter src into dst-sorted es via global cursors -----------------
__global__ __launch_bounds__(256)
void k_scatter(const int* __restrict__ src, const int* __restrict__ dst,
               int* __restrict__ cursor, int* __restrict__ es, int E) {
    int e0 = blockIdx.x * CHUNK + threadIdx.x;
#pragma unroll
    for (int i = 0; i < EPT; ++i) {
        int e = e0 + i * 256;
        if (e < E) {
            int s = NTL(src + e);
            int d = NTL(dst + e);
            int off = atomicAdd(&cursor[d], 1);
            es[off] = s;                  // normal store: L2 combines
        }
    }
}

// ---- gather helper: accumulate 8 halves into fp32 --------------------------
__device__ inline void acc8(uint4 u, float* s) {
    __half2 h0 = *(__half2*)&u.x, h1 = *(__half2*)&u.y;
    __half2 h2 = *(__half2*)&u.z, h3 = *(__half2*)&u.w;
    float2 f0 = __half22float2(h0), f1 = __half22float2(h1);
    float2 f2 = __half22float2(h2), f3 = __half22float2(h3);
    s[0] += f0.x; s[1] += f0.y; s[2] += f1.x; s[3] += f1.y;
    s[4] += f2.x; s[5] += f2.y; s[6] += f3.x; s[7] += f3.y;
}

// ---- gather core: s[8] = self + sum over edge list (fp32 accum) ------------
// 16 gathers in flight (R17).
__device__ inline void gather32(const int* __restrict__ starts,
                                const int* __restrict__ es,
                                const uint4* __restrict__ g4,
                                int node, int lane, float* s) {
    acc8(g4[(size_t)node * 4 + lane], s);  // self term
    int j = starts[node], end = starts[node + 1];
    while (j < end && (j & 3)) {           // align to int4 boundary
        acc8(g4[(size_t)es[j] * 4 + lane], s);
        ++j;
    }
    for (; j + 16 <= end; j += 16) {       // 16 gathers in flight
        int4 e0 = *(const int4*)(es + j);
        int4 e1 = *(const int4*)(es + j + 4);
        int4 e2 = *(const int4*)(es + j + 8);
        int4 e3 = *(const int4*)(es + j + 12);
        uint4 u0  = g4[(size_t)e0.x * 4 + lane];
        uint4 u1  = g4[(size_t)e0.y * 4 + lane];
        uint4 u2  = g4[(size_t)e0.z * 4 + lane];
        uint4 u3  = g4[(size_t)e0.w * 4 + lane];
        uint4 u4  = g4[(size_t)e1.x * 4 + lane];
        uint4 u5  = g4[(size_t)e1.y * 4 + lane];
        uint4 u6  = g4[(size_t)e1.z * 4 + lane];
        uint4 u7  = g4[(size_t)e1.w * 4 + lane];
        uint4 u8  = g4[(size_t)e2.x * 4 + lane];
        uint4 u9  = g4[(size_t)e2.y * 4 + lane];
        uint4 u10 = g4[(size_t)e2.z * 4 + lane];
        uint4 u11 = g4[(size_t)e2.w * 4 + lane];
        uint4 u12 = g4[(size_t)e3.x * 4 + lane];
        uint4 u13 = g4[(size_t)e3.y * 4 + lane];
        uint4 u14 = g4[(size_t)e3.z * 4 + lane];
        uint4 u15 = g4[(size_t)e3.w * 4 + lane];
        acc8(u0, s);  acc8(u1, s);  acc8(u2, s);  acc8(u3, s);
        acc8(u4, s);  acc8(u5, s);  acc8(u6, s);  acc8(u7, s);
        acc8(u8, s);  acc8(u9, s);  acc8(u10, s); acc8(u11, s);
        acc8(u12, s); acc8(u13, s); acc8(u14, s); acc8(u15, s);
    }
    if (j + 8 <= end) {
        int4 e0 = *(const int4*)(es + j);
        int4 e1 = *(const int4*)(es + j + 4);
        uint4 u0 = g4[(size_t)e0.x * 4 + lane];
        uint4 u1 = g4[(size_t)e0.y * 4 + lane];
        uint4 u2 = g4[(size_t)e0.z * 4 + lane];
        uint4 u3 = g4[(size_t)e0.w * 4 + lane];
        uint4 u4 = g4[(size_t)e1.x * 4 + lane];
        uint4 u5 = g4[(size_t)e1.y * 4 + lane];
        uint4 u6 = g4[(size_t)e1.z * 4 + lane];
        uint4 u7 = g4[(size_t)e1.w * 4 + lane];
        acc8(u0, s); acc8(u1, s); acc8(u2, s); acc8(u3, s);
        acc8(u4, s); acc8(u5, s); acc8(u6, s); acc8(u7, s);
        j += 8;
    }
    if (j + 4 <= end) {
        int4 e0 = *(const int4*)(es + j);
        uint4 u0 = g4[(size_t)e0.x * 4 + lane];
        uint4 u1 = g4[(size_t)e0.y * 4 + lane];
        uint4 u2 = g4[(size_t)e0.z * 4 + lane];
        uint4 u3 = g4[(size_t)e0.w * 4 + lane];
        acc8(u0, s); acc8(u1, s); acc8(u2, s); acc8(u3, s);
        j += 4;
    }
    for (; j < end; ++j) acc8(g4[(size_t)es[j] * 4 + lane], s);
}

// ---- fused hidden layer: gout = fp16(dis (.) relu(agg(g) @ W + b)) ---------
__global__ __launch_bounds__(256)
void k_fused16(const int* __restrict__ starts, const int* __restrict__ es,
               const float* __restrict__ dis, const __half* __restrict__ g,
               const float* __restrict__ W, const float* __restrict__ bias,
               __half* __restrict__ gout, int n) {
    __shared__ float Ws[32][33];
    __shared__ float Xs[64][33];
    int t = threadIdx.x;
    for (int i = t; i < 1024; i += 256) Ws[i >> 5][i & 31] = W[i];
    int r = t >> 2, lane = t & 3;
    int node = blockIdx.x * 64 + r;
    bool alive = node < n;
    float dd = 0.f;
    if (alive) {
        float s[8] = {0, 0, 0, 0, 0, 0, 0, 0};
        gather32(starts, es, (const uint4*)g, node, lane, s);
        dd = dis[node];
#pragma unroll
        for (int i = 0; i < 8; ++i) Xs[r][lane * 8 + i] = dd * s[i];
    }
    __syncthreads();                       // covers Ws and Xs
    if (alive) {
        int c0 = lane * 8;
        float acc[8];
#pragma unroll
        for (int i = 0; i < 8; ++i) acc[i] = bias[c0 + i];
#pragma unroll 8
        for (int k = 0; k < 32; ++k) {
            float xv = Xs[r][k];
#pragma unroll
            for (int i = 0; i < 8; ++i) acc[i] += xv * Ws[k][c0 + i];
        }
        __half2 h0 = __floats2half2_rn(dd * fmaxf(acc[0], 0.f), dd * fmaxf(acc[1], 0.f));
        __half2 h1 = __floats2half2_rn(dd * fmaxf(acc[2], 0.f), dd * fmaxf(acc[3], 0.f));
        __half2 h2 = __floats2half2_rn(dd * fmaxf(acc[4], 0.f), dd * fmaxf(acc[5], 0.f));
        __half2 h3 = __floats2half2_rn(dd * fmaxf(acc[6], 0.f), dd * fmaxf(acc[7], 0.f));
        uint4 u;
        u.x = *(unsigned int*)&h0; u.y = *(unsigned int*)&h1;
        u.z = *(unsigned int*)&h2; u.w = *(unsigned int*)&h3;
        ((uint4*)gout)[(size_t)node * 4 + lane] = u;
    }
}

// ---- fused output layer: out = [agg(g) @ Wmu + bmu | agg(g) @ Wlv + blv] ---
__global__ __launch_bounds__(256)
void k_fused_final(const int* __restrict__ starts, const int* __restrict__ es,
                   const float* __restrict__ dis, const __half* __restrict__ g,
                   const float* __restrict__ Wmu, const float* __restrict__ Wlv,
                   const float* __restrict__ bmu, const float* __restrict__ blv,
                   float* __restrict__ out, int n) {
    __shared__ float Ws[32][66];           // [k][c], mu cols 0-31, lv cols 32-63
    __shared__ float Xs[64][33];
    int t = threadIdx.x;
    for (int i = t; i < 1024; i += 256) {
        Ws[i >> 5][i & 31]        = Wmu[i];
        Ws[i >> 5][32 + (i & 31)] = Wlv[i];
    }
    int r = t >> 2, lane = t & 3;
    int node = blockIdx.x * 64 + r;
    bool alive = node < n;
    if (alive) {
        float s[8] = {0, 0, 0, 0, 0, 0, 0, 0};
        gather32(starts, es, (const uint4*)g, node, lane, s);
        float dd = dis[node];
#pragma unroll
        for (int i = 0; i < 8; ++i) Xs[r][lane * 8 + i] = dd * s[i];
    }
    __syncthreads();
    if (alive) {
        int c0 = lane * 8;
        float am[8], al[8];
#pragma unroll
        for (int i = 0; i < 8; ++i) { am[i] = bmu[c0 + i]; al[i] = blv[c0 + i]; }
#pragma unroll 4
        for (int k = 0; k < 32; ++k) {
            float xv = Xs[r][k];
#pragma unroll
            for (int i = 0; i < 8; ++i) {
                am[i] += xv * Ws[k][c0 + i];
                al[i] += xv * Ws[k][32 + c0 + i];
            }
        }
        float4* om = (float4*)out + (size_t)node * 8 + lane * 2;
        om[0] = make_float4(am[0], am[1], am[2], am[3]);
        om[1] = make_float4(am[4], am[5], am[6], am[7]);
        float4* ol = (float4*)(out + (size_t)n * 32) + (size_t)node * 8 + lane * 2;
        ol[0] = make_float4(al[0], al[1], al[2], al[3]);
        ol[1] = make_float4(al[4], al[5], al[6], al[7]);
    }
}

// ---- launch ----------------------------------------------------------------

extern "C" void kernel_launch(void* const* d_in, const int* in_sizes, int n_in,
                              void* d_out, int out_size, void* d_ws, size_t ws_size,
                              hipStream_t stream) {
    const float* x   = (const float*)d_in[0];
    const int*   ei  = (const int*)d_in[1];
    const float* W1  = (const float*)d_in[2];
    const float* b1  = (const float*)d_in[3];
    const float* W2  = (const float*)d_in[4];
    const float* b2  = (const float*)d_in[5];
    const float* Wmu = (const float*)d_in[6];
    const float* bmu = (const float*)d_in[7];
    const float* Wlv = (const float*)d_in[8];
    const float* blv = (const float*)d_in[9];
    float* out = (float*)d_out;

    int n = in_sizes[0] / 32;   // 100000
    int E = in_sizes[1] / 2;    // 1600000
    const int* src = ei;
    const int* dst = ei + E;

    // workspace layout (all segments 16B-aligned)
    int     npad   = (n + 8) & ~3;                    // covers n+1, 4-aligned
    int*    deg    = (int*)d_ws;                      // npad
    int*    cursor = deg + npad;                      // npad
    int*    tmp    = cursor + npad;                   // npad (local scans)
    int*    bsum   = tmp + npad;                      // 512
    int*    starts = bsum + 512;                      // npad (n+1 used)
    float*  dis    = (float*)(starts + npad);         // npad
    int*    es     = (int*)(dis + npad);              // E
    __half* gA     = (__half*)(es + E);               // n*32 fp16
    __half* gB     = gA + (size_t)n * 32;             // n*32 fp16

    int eblk  = (E + CHUNK - 1) / CHUNK;              // 391
    int nscan = (npad + 1023) / 1024;                 // 98
    int nout  = (n + 256) / 256;                      // 391 (covers node n)
    int agrid = (n + 63) / 64;                        // 1563

    // ---- edge preprocessing (flat, massively parallel) ----
    hipMemsetAsync(deg, 0, (size_t)npad * sizeof(int), stream);
    k_deg<<<eblk, 256, 0, stream>>>(dst, deg, E);
    k_scan1<<<nscan, 256, 0, stream>>>(deg, tmp, bsum, npad);
    k_scanout<<<nout, 256, 0, stream>>>(deg, tmp, bsum, starts, cursor, dis, x, gA, n, E);
    k_scatter<<<eblk, 256, 0, stream>>>(src, dst, cursor, es, E);

    // ---- layer 1 (agg + gemm fused) ----
    k_fused16<<<agrid, 256, 0, stream>>>(starts, es, dis, gA, W1, b1, gB, n);
    // ---- layer 2 ----
    k_fused16<<<agrid, 256, 0, stream>>>(starts, es, dis, gB, W2, b2, gA, n);
    // ---- mu/logvar ----
    k_fused_final<<<agrid, 256, 0, stream>>>(starts, es, dis, gA, Wmu, Wlv, bmu, blv, out, n);
}

// Round 8
// 272.890 us; speedup vs baseline: 1.2839x; 1.2839x over previous
//
#include <hip/hip_runtime.h>
#include <hip/hip_fp16.h>

// ---------------------------------------------------------------------------
// VGAE encoder, gather-form, fp16 gather table.
//   a[i] = dis_i*(g[i] + sum_{e:dst=i} g[src_e]),  g = fp16(dis (.) h)
// R12: agg+GEMM fused per 64-node block via LDS epilogue (294 -> 249 us).
// R13 FAILED: coop mega-kernel (occupancy halved; latency-bound).
// R14 FAILED: degree-sort perm (scattered locality).
// R15 FAILED: 8x-split finalize (duplicated histograms).
// R17: 16-deep gather ILP: only -4.4 -> not latency/ILP-bound.
// R18 FAILED: flat global-atomic preproc = +106 us; k_scatter's random 4B
//   stores from 8 XCDs thrashed L2 (106 MB writebacks of a 6.4 MB buffer).
//   CALIBRATION: R1 bucket+finalize preproc is only ~10-20 us. Budget is
//   ~44 fill + 3x46 gather + ~15 preproc + ~30 boundaries.
// R19: SRC-PHASE-SPLIT gather. 97 MB L2-fills/layer (table 6.4 MB > 4 MB
//   per-XCD L2) = saturated L2<->L3 fill port. Split src at mid=n/2: each
//   layer = A (gather src<mid -> fp32 partials) + B (resume, gather
//   src>=mid, GEMM). 3.2 MB working set fits L2; dispatch boundary makes
//   phase discipline structural. k_finalize: 1024-bin hist -> es sorted
//   (dst, half), per-node mid[] pointer.
//   NT loads ONLY on read-once streams (src/dst). NT stores banned (R10).
// ---------------------------------------------------------------------------

#define BK_BITS 9
#define BK      (1 << BK_BITS)     // 512 dst nodes per bucket
#define BMASK   (BK - 1)
#define EPT     16
#define CHUNK   (256 * EPT)        // 4096 edges per block
#define CAP     16384              // bucket capacity (mean 8192, max ~8.6k)

typedef int   vint4   __attribute__((ext_vector_type(4)));
typedef uint  vuint4  __attribute__((ext_vector_type(4)));
typedef float vfloat4 __attribute__((ext_vector_type(4)));

#define NTL(p) __builtin_nontemporal_load(p)

// ---- pass A: scatter edges into capacity-padded dst-buckets ----------------
__global__ void k_bucket(const int* __restrict__ src, const int* __restrict__ dst,
                         int* __restrict__ bcur, int* __restrict__ ebuf, int E) {
    __shared__ int lcnt[256];
    __shared__ int lbase[256];
    int t = threadIdx.x;
    lcnt[t] = 0;
    __syncthreads();
    int e0 = blockIdx.x * CHUNK;
    int pk[EPT];
#pragma unroll
    for (int i = 0; i < EPT; ++i) {
        int e = e0 + i * 256 + t;
        pk[i] = -1;
        if (e < E) {
            int d = NTL(dst + e);
            int b = d >> BK_BITS;
            int off = atomicAdd(&lcnt[b], 1);          // off < CHUNK = 4096
            pk[i] = (b << 21) | (off << BK_BITS) | (d & BMASK);
        }
    }
    __syncthreads();
    lbase[t] = t * CAP + atomicAdd(&bcur[t], lcnt[t]);
    __syncthreads();
#pragma unroll
    for (int i = 0; i < EPT; ++i) {
        int e = e0 + i * 256 + t;
        if (e < E) {
            int b   = pk[i] >> 21;
            int off = (pk[i] >> BK_BITS) & 4095;
            int dl  = pk[i] & BMASK;
            int pos = lbase[b] + off;
            if (pos < (b + 1) * CAP)                  // overflow guard (never hit)
                ebuf[pos] = (NTL(src + e) << BK_BITS) | dl;
        }
    }
}

// ---- pass B: per-bucket finalize: starts/mid/dis, (dst,half)-sorted es, g0 -
__global__ void k_finalize(const int* __restrict__ bcur, int* __restrict__ starts,
                           int* __restrict__ midp, float* __restrict__ dis,
                           const int* __restrict__ ebuf, int* __restrict__ es,
                           const float* __restrict__ x, __half* __restrict__ g0,
                           int n, int E, int mid) {
    __shared__ int   hist[2 * BK];   // 1024 (dst-local, half) bins
    __shared__ int   sc2[BK];        // pair sums for scan
    __shared__ int   sb[256];
    __shared__ float disL[BK];
    int b = blockIdx.x, t = threadIdx.x;
    if (t < 256) sb[t] = min(bcur[t], CAP);
    hist[t] = 0;
    hist[t + BK] = 0;
    __syncthreads();
    for (int o = 1; o < 256; o <<= 1) {
        int xv = 0;
        if (t < 256 && t >= o) xv = sb[t - o];
        __syncthreads();
        if (t < 256) sb[t] += xv;
        __syncthreads();
    }
    int cnt = min(bcur[b], CAP);
    int beg = sb[b] - cnt;                  // exclusive scan at b
    const int* eb = ebuf + (size_t)b * CAP;
    for (int j = t; j < cnt; j += BK) {
        int v = eb[j];
        int bin = ((v & BMASK) << 1) | ((v >> BK_BITS) >= mid ? 1 : 0);
        atomicAdd(&hist[bin], 1);
    }
    __syncthreads();
    // pairwise scan of 1024 bins with 512 threads; thread t owns node t
    int a0 = hist[2 * t], a1 = hist[2 * t + 1];
    int ps = a0 + a1;
    sc2[t] = ps;
    __syncthreads();
    for (int o = 1; o < BK; o <<= 1) {
        int xv = (t >= o) ? sc2[t - o] : 0;
        __syncthreads();
        sc2[t] += xv;
        __syncthreads();
    }
    int base = sc2[t] - ps;                 // exclusive offset at node t
    int gnode = (b << BK_BITS) + t;
    float dv = rsqrtf((float)ps + 1.0f);    // +1 = self loop
    disL[t] = dv;
    if (gnode < n) {
        starts[gnode] = beg + base;
        midp[gnode]   = beg + base + a0;
        dis[gnode] = dv;
    }
    if (b == 0 && t == 0) starts[n] = E;
    __syncthreads();                        // hist reads done before reuse
    hist[2 * t]     = base;                 // reuse as cursors
    hist[2 * t + 1] = base + a0;
    __syncthreads();
    for (int j = t; j < cnt; j += BK) {
        int v = eb[j];
        int bin = ((v & BMASK) << 1) | ((v >> BK_BITS) >= mid ? 1 : 0);
        int off = atomicAdd(&hist[bin], 1);
        es[beg + off] = v >> BK_BITS;       // normal store: L2 combines
    }
    // g0 = fp16(dis (.) x) for this bucket's nodes (coalesced 8 B stores)
    int node0 = b << BK_BITS;
    const float4* x4 = (const float4*)x;
    uint2* g2 = (uint2*)g0;
    for (int idx = t; idx < BK * 8; idx += BK) {
        int r = idx >> 3, lane = idx & 7;
        int nd = node0 + r;
        if (nd < n) {
            float d = disL[r];
            float4 v = x4[(size_t)nd * 8 + lane];
            __half2 lo = __floats2half2_rn(d * v.x, d * v.y);
            __half2 hi = __floats2half2_rn(d * v.z, d * v.w);
            uint2 u;
            u.x = *(unsigned int*)&lo;
            u.y = *(unsigned int*)&hi;
            g2[(size_t)nd * 8 + lane] = u;
        }
    }
}

// ---- gather helper: accumulate 8 halves into fp32 --------------------------
__device__ inline void acc8(uint4 u, float* s) {
    __half2 h0 = *(__half2*)&u.x, h1 = *(__half2*)&u.y;
    __half2 h2 = *(__half2*)&u.z, h3 = *(__half2*)&u.w;
    float2 f0 = __half22float2(h0), f1 = __half22float2(h1);
    float2 f2 = __half22float2(h2), f3 = __half22float2(h3);
    s[0] += f0.x; s[1] += f0.y; s[2] += f1.x; s[3] += f1.y;
    s[4] += f2.x; s[5] += f2.y; s[6] += f3.x; s[7] += f3.y;
}

// ---- gather over an index range [j, end): 16 gathers in flight -------------
__device__ inline void gather_range(const int* __restrict__ es,
                                    const uint4* __restrict__ g4,
                                    int j, int end, int lane, float* s) {
    while (j < end && (j & 3)) {           // align to int4 boundary
        acc8(g4[(size_t)es[j] * 4 + lane], s);
        ++j;
    }
    for (; j + 16 <= end; j += 16) {
        int4 e0 = *(const int4*)(es + j);
        int4 e1 = *(const int4*)(es + j + 4);
        int4 e2 = *(const int4*)(es + j + 8);
        int4 e3 = *(const int4*)(es + j + 12);
        uint4 u0  = g4[(size_t)e0.x * 4 + lane];
        uint4 u1  = g4[(size_t)e0.y * 4 + lane];
        uint4 u2  = g4[(size_t)e0.z * 4 + lane];
        uint4 u3  = g4[(size_t)e0.w * 4 + lane];
        uint4 u4  = g4[(size_t)e1.x * 4 + lane];
        uint4 u5  = g4[(size_t)e1.y * 4 + lane];
        uint4 u6  = g4[(size_t)e1.z * 4 + lane];
        uint4 u7  = g4[(size_t)e1.w * 4 + lane];
        uint4 u8  = g4[(size_t)e2.x * 4 + lane];
        uint4 u9  = g4[(size_t)e2.y * 4 + lane];
        uint4 u10 = g4[(size_t)e2.z * 4 + lane];
        uint4 u11 = g4[(size_t)e2.w * 4 + lane];
        uint4 u12 = g4[(size_t)e3.x * 4 + lane];
        uint4 u13 = g4[(size_t)e3.y * 4 + lane];
        uint4 u14 = g4[(size_t)e3.z * 4 + lane];
        uint4 u15 = g4[(size_t)e3.w * 4 + lane];
        acc8(u0, s);  acc8(u1, s);  acc8(u2, s);  acc8(u3, s);
        acc8(u4, s);  acc8(u5, s);  acc8(u6, s);  acc8(u7, s);
        acc8(u8, s);  acc8(u9, s);  acc8(u10, s); acc8(u11, s);
        acc8(u12, s); acc8(u13, s); acc8(u14, s); acc8(u15, s);
    }
    if (j + 8 <= end) {
        int4 e0 = *(const int4*)(es + j);
        int4 e1 = *(const int4*)(es + j + 4);
        uint4 u0 = g4[(size_t)e0.x * 4 + lane];
        uint4 u1 = g4[(size_t)e0.y * 4 + lane];
        uint4 u2 = g4[(size_t)e0.z * 4 + lane];
        uint4 u3 = g4[(size_t)e0.w * 4 + lane];
        uint4 u4 = g4[(size_t)e1.x * 4 + lane];
        uint4 u5 = g4[(size_t)e1.y * 4 + lane];
        uint4 u6 = g4[(size_t)e1.z * 4 + lane];
        uint4 u7 = g4[(size_t)e1.w * 4 + lane];
        acc8(u0, s); acc8(u1, s); acc8(u2, s); acc8(u3, s);
        acc8(u4, s); acc8(u5, s); acc8(u6, s); acc8(u7, s);
        j += 8;
    }
    if (j + 4 <= end) {
        int4 e0 = *(const int4*)(es + j);
        uint4 u0 = g4[(size_t)e0.x * 4 + lane];
        uint4 u1 = g4[(size_t)e0.y * 4 + lane];
        uint4 u2 = g4[(size_t)e0.z * 4 + lane];
        uint4 u3 = g4[(size_t)e0.w * 4 + lane];
        acc8(u0, s); acc8(u1, s); acc8(u2, s); acc8(u3, s);
        j += 4;
    }
    for (; j < end; ++j) acc8(g4[(size_t)es[j] * 4 + lane], s);
}

// ---- phase A: partials = self + sum over lo-half srcs (working set 3.2 MB) -
__global__ __launch_bounds__(256)
void k_gA(const int* __restrict__ starts, const int* __restrict__ midp,
          const int* __restrict__ es, const __half* __restrict__ g,
          float* __restrict__ part, int n) {
    int t = threadIdx.x;
    int r = t >> 2, lane = t & 3;
    int node = blockIdx.x * 64 + r;
    if (node >= n) return;
    float s[8] = {0, 0, 0, 0, 0, 0, 0, 0};
    const uint4* g4 = (const uint4*)g;
    acc8(g4[(size_t)node * 4 + lane], s);  // self term
    gather_range(es, g4, starts[node], midp[node], lane, s);
    float4* p = (float4*)part + (size_t)node * 8 + lane * 2;
    p[0] = make_float4(s[0], s[1], s[2], s[3]);
    p[1] = make_float4(s[4], s[5], s[6], s[7]);
}

// ---- phase B hidden: resume partials, hi-half gather, GEMM -----------------
__global__ __launch_bounds__(256)
void k_f16B(const int* __restrict__ starts, const int* __restrict__ midp,
            const int* __restrict__ es, const float* __restrict__ dis,
            const __half* __restrict__ g, const float* __restrict__ part,
            const float* __restrict__ W, const float* __restrict__ bias,
            __half* __restrict__ gout, int n) {
    __shared__ float Ws[32][33];
    __shared__ float Xs[64][33];
    int t = threadIdx.x;
    for (int i = t; i < 1024; i += 256) Ws[i >> 5][i & 31] = W[i];
    int r = t >> 2, lane = t & 3;
    int node = blockIdx.x * 64 + r;
    bool alive = node < n;
    float dd = 0.f;
    if (alive) {
        const float4* p = (const float4*)part + (size_t)node * 8 + lane * 2;
        float4 p0 = p[0], p1 = p[1];
        float s[8] = {p0.x, p0.y, p0.z, p0.w, p1.x, p1.y, p1.z, p1.w};
        gather_range(es, (const uint4*)g, midp[node], starts[node + 1], lane, s);
        dd = dis[node];
#pragma unroll
        for (int i = 0; i < 8; ++i) Xs[r][lane * 8 + i] = dd * s[i];
    }
    __syncthreads();                       // covers Ws and Xs
    if (alive) {
        int c0 = lane * 8;
        float acc[8];
#pragma unroll
        for (int i = 0; i < 8; ++i) acc[i] = bias[c0 + i];
#pragma unroll 8
        for (int k = 0; k < 32; ++k) {
            float xv = Xs[r][k];
#pragma unroll
            for (int i = 0; i < 8; ++i) acc[i] += xv * Ws[k][c0 + i];
        }
        __half2 h0 = __floats2half2_rn(dd * fmaxf(acc[0], 0.f), dd * fmaxf(acc[1], 0.f));
        __half2 h1 = __floats2half2_rn(dd * fmaxf(acc[2], 0.f), dd * fmaxf(acc[3], 0.f));
        __half2 h2 = __floats2half2_rn(dd * fmaxf(acc[4], 0.f), dd * fmaxf(acc[5], 0.f));
        __half2 h3 = __floats2half2_rn(dd * fmaxf(acc[6], 0.f), dd * fmaxf(acc[7], 0.f));
        uint4 u;
        u.x = *(unsigned int*)&h0; u.y = *(unsigned int*)&h1;
        u.z = *(unsigned int*)&h2; u.w = *(unsigned int*)&h3;
        ((uint4*)gout)[(size_t)node * 4 + lane] = u;
    }
}

// ---- phase B output: resume, hi gather, dual GEMM --------------------------
__global__ __launch_bounds__(256)
void k_ffinB(const int* __restrict__ starts, const int* __restrict__ midp,
             const int* __restrict__ es, const float* __restrict__ dis,
             const __half* __restrict__ g, const float* __restrict__ part,
             const float* __restrict__ Wmu, const float* __restrict__ Wlv,
             const float* __restrict__ bmu, const float* __restrict__ blv,
             float* __restrict__ out, int n) {
    __shared__ float Ws[32][66];           // [k][c], mu cols 0-31, lv cols 32-63
    __shared__ float Xs[64][33];
    int t = threadIdx.x;
    for (int i = t; i < 1024; i += 256) {
        Ws[i >> 5][i & 31]        = Wmu[i];
        Ws[i >> 5][32 + (i & 31)] = Wlv[i];
    }
    int r = t >> 2, lane = t & 3;
    int node = blockIdx.x * 64 + r;
    bool alive = node < n;
    if (alive) {
        const float4* p = (const float4*)part + (size_t)node * 8 + lane * 2;
        float4 p0 = p[0], p1 = p[1];
        float s[8] = {p0.x, p0.y, p0.z, p0.w, p1.x, p1.y, p1.z, p1.w};
        gather_range(es, (const uint4*)g, midp[node], starts[node + 1], lane, s);
        float dd = dis[node];
#pragma unroll
        for (int i = 0; i < 8; ++i) Xs[r][lane * 8 + i] = dd * s[i];
    }
    __syncthreads();
    if (alive) {
        int c0 = lane * 8;
        float am[8], al[8];
#pragma unroll
        for (int i = 0; i < 8; ++i) { am[i] = bmu[c0 + i]; al[i] = blv[c0 + i]; }
#pragma unroll 4
        for (int k = 0; k < 32; ++k) {
            float xv = Xs[r][k];
#pragma unroll
            for (int i = 0; i < 8; ++i) {
                am[i] += xv * Ws[k][c0 + i];
                al[i] += xv * Ws[k][32 + c0 + i];
            }
        }
        float4* om = (float4*)out + (size_t)node * 8 + lane * 2;
        om[0] = make_float4(am[0], am[1], am[2], am[3]);
        om[1] = make_float4(am[4], am[5], am[6], am[7]);
        float4* ol = (float4*)(out + (size_t)n * 32) + (size_t)node * 8 + lane * 2;
        ol[0] = make_float4(al[0], al[1], al[2], al[3]);
        ol[1] = make_float4(al[4], al[5], al[6], al[7]);
    }
}

// ---- launch ----------------------------------------------------------------

extern "C" void kernel_launch(void* const* d_in, const int* in_sizes, int n_in,
                              void* d_out, int out_size, void* d_ws, size_t ws_size,
                              hipStream_t stream) {
    const float* x   = (const float*)d_in[0];
    const int*   ei  = (const int*)d_in[1];
    const float* W1  = (const float*)d_in[2];
    const float* b1  = (const float*)d_in[3];
    const float* W2  = (const float*)d_in[4];
    const float* b2  = (const float*)d_in[5];
    const float* Wmu = (const float*)d_in[6];
    const float* bmu = (const float*)d_in[7];
    const float* Wlv = (const float*)d_in[8];
    const float* blv = (const float*)d_in[9];
    float* out = (float*)d_out;

    int n = in_sizes[0] / 32;   // 100000
    int E = in_sizes[1] / 2;    // 1600000
    const int* src = ei;
    const int* dst = ei + E;
    int nbuck = (n + BK - 1) >> BK_BITS;   // 196 (<= 256)
    int mid = n / 2;                       // src-space split point

    // workspace layout (all segments 16B-aligned)
    int*    bcur   = (int*)d_ws;                      // 256
    int     npad   = (n + 8) & ~3;
    int*    starts = bcur + 256;                      // npad (n+1 used)
    int*    midp   = starts + npad;                   // npad
    float*  dis    = (float*)(midp + npad);           // npad
    int*    es     = (int*)(dis + npad);              // E
    __half* gA     = (__half*)(es + E);               // n*32 fp16
    __half* gB     = gA + (size_t)n * 32;             // n*32 fp16
    float*  part   = (float*)(gB + (size_t)n * 32);   // n*32 fp32 (12.8 MB)
    int*    ebuf   = (int*)(part + (size_t)n * 32);   // 256*CAP ints (16.8 MB)

    int nblk  = (E + CHUNK - 1) / CHUNK;   // 391
    int agrid = (n + 63) / 64;             // 1563

    // ---- edge preprocessing ----
    hipMemsetAsync(bcur, 0, 256 * sizeof(int), stream);
    k_bucket<<<nblk, 256, 0, stream>>>(src, dst, bcur, ebuf, E);
    k_finalize<<<nbuck, BK, 0, stream>>>(bcur, starts, midp, dis, ebuf, es, x, gA, n, E, mid);

    // ---- layer 1: lo-phase partials, then hi-phase + GEMM ----
    k_gA<<<agrid, 256, 0, stream>>>(starts, midp, es, gA, part, n);
    k_f16B<<<agrid, 256, 0, stream>>>(starts, midp, es, dis, gA, part, W1, b1, gB, n);
    // ---- layer 2 ----
    k_gA<<<agrid, 256, 0, stream>>>(starts, midp, es, gB, part, n);
    k_f16B<<<agrid, 256, 0, stream>>>(starts, midp, es, dis, gB, part, W2, b2, gA, n);
    // ---- mu/logvar ----
    k_gA<<<agrid, 256, 0, stream>>>(starts, midp, es, gA, part, n);
    k_ffinB<<<agrid, 256, 0, stream>>>(starts, midp, es, dis, gA, part, Wmu, Wlv, bmu, blv, out, n);
}